// Round 1
// 278.041 us; speedup vs baseline: 1.1385x; 1.1385x over previous
//
#include <hip/hip_runtime.h>
#include <hip/hip_bf16.h>

// TreeRNN: K=8, DEPTH=7, N=299593, V=32000, X=H=O=128.
// bf16 MFMA 16x16x32, fp32 accumulate.
// Key structure (this round): h never touches HBM. Each level computes the
// 8-child sums of its own h tile (already in LDS for the W_out GEMM) and
// writes one bf16 "childsum" row per parent; the parent level loads its
// U-GEMM A-fragments straight from that row. A-fragments for the embed GEMM
// are loaded directly from a pre-converted bf16 emb table (per-lane row =
// coll), so the LDS staging phase + barrier are gone entirely. LDS holds
// only the h tile (transpose for GEMM3 + childsum reduction).
// Alignment fact that makes this work: s_l - 1 = 8*s_{l-1}, so every 64-row
// block is exactly the children of 8 consecutive parents.

typedef __bf16 bf16x8 __attribute__((ext_vector_type(8)));
typedef float f32x4 __attribute__((ext_vector_type(4)));
typedef float f32x2 __attribute__((ext_vector_type(2)));
typedef unsigned short ushort8 __attribute__((ext_vector_type(8)));
typedef unsigned int uint2v __attribute__((ext_vector_type(2)));

#define NNODES 299593
#define NPAR   37449   // nodes 0..37448 have children

static __device__ __forceinline__ unsigned short f2bf(float f) {
  union { float f; unsigned int u; } v; v.f = f;
  unsigned int u = v.u;
  u += 0x7fff + ((u >> 16) & 1);   // RNE
  return (unsigned short)(u >> 16);
}

// pack 2 floats -> 2 bf16 in one dword (a -> low, b -> high)
static __device__ __forceinline__ unsigned int pk2bf(float a, float b) {
#if __has_builtin(__builtin_amdgcn_cvt_pk_bf16_f32)
  typedef __bf16 bf16x2 __attribute__((ext_vector_type(2)));
  union { bf16x2 v; unsigned int u; } c;
  c.v = __builtin_amdgcn_cvt_pk_bf16_f32(a, b);
  return c.u;
#else
  return (unsigned int)f2bf(a) | ((unsigned int)f2bf(b) << 16);
#endif
}

// tanh(x) = 1 - 2/(1+e^{2x})
static __device__ __forceinline__ float fast_tanh(float x) {
  float y = x * 2.885390081777927f;  // 2*log2(e)
#if __has_builtin(__builtin_amdgcn_exp2f)
  float e = __builtin_amdgcn_exp2f(y);
#else
  float e = __builtin_exp2f(y);
#endif
#if __has_builtin(__builtin_amdgcn_rcpf)
  float r = __builtin_amdgcn_rcpf(e + 1.0f);
#else
  float r = 1.0f / (e + 1.0f);
#endif
  return __builtin_fmaf(-2.0f, r, 1.0f);
}

// Swizzle W (128x128 row-major fp32) into B-fragment order for
// v_mfma_f32_16x16x32_bf16: frag f = ((kt*8+nt)*64 + lane)*8 + j
// holds W[kt*32 + (lane>>4)*8 + j][nt*16 + (lane&15)].
// Also converts emb (32000x128 fp32) -> bf16 once.
__global__ __launch_bounds__(256) void prep_kernel(
    const float* __restrict__ W_in, const float* __restrict__ U,
    const float* __restrict__ W_out, const float* __restrict__ emb,
    unsigned short* __restrict__ w_sw, unsigned short* __restrict__ emb_bf) {
  int t = blockIdx.x * 256 + threadIdx.x;
  if (blockIdx.x < 192) {              // 49152 weight elements
    int f = t;
    int m = f >> 14;
    int r = f & 16383;
    int j = r & 7;
    int lane = (r >> 3) & 63;
    int nt = (r >> 9) & 7;
    int kt = (r >> 12) & 3;
    int k = kt * 32 + ((lane >> 4) * 8) + j;
    int n = nt * 16 + (lane & 15);
    const float* W = (m == 0) ? W_in : (m == 1) ? U : W_out;
    w_sw[f] = f2bf(W[k * 128 + n]);
  } else {                              // 4,096,000 emb elements, 8 per thread
    size_t i = (size_t)(t - 49152) * 8;
    f32x4 v0 = *(const f32x4*)(emb + i);
    f32x4 v1 = *(const f32x4*)(emb + i + 4);
    union { ushort8 s; unsigned int u[4]; } w;
    w.u[0] = pk2bf(v0[0], v0[1]);
    w.u[1] = pk2bf(v0[2], v0[3]);
    w.u[2] = pk2bf(v1[0], v1[1]);
    w.u[3] = pk2bf(v1[2], v1[3]);
    *(ushort8*)(emb_bf + i) = w.s;
  }
}

// load a 16B bf16 A-fragment, zeroed when !nz (per-lane predicate)
static __device__ __forceinline__ bf16x8 ldz(const unsigned short* p, int nz) {
  union { bf16x8 b; unsigned int u[4]; } v;
  v.b = *(const bf16x8*)p;
  if (!nz) { v.u[0] = 0; v.u[1] = 0; v.u[2] = 0; v.u[3] = 0; }
  return v.b;
}

// one K-block (kt) of a 16x128 MFMA row: 8 nt tiles, B frags from
// pre-swizzled global (L1/L2-resident, 32 KB/matrix)
static __device__ __forceinline__ void mfma_row8(f32x4 acc[8], bf16x8 a,
    const unsigned short* __restrict__ bkt, int lane) {
#pragma unroll
  for (int nt = 0; nt < 8; ++nt) {
    bf16x8 b = *(const bf16x8*)(bkt + nt * 512 + lane * 8);
    acc[nt] = __builtin_amdgcn_mfma_f32_16x16x32_bf16(a, b, acc[nt], 0, 0, 0);
  }
}

template <bool LEAF>
static __device__ __forceinline__ void tile_body(
    const int* __restrict__ x, const int* __restrict__ mask,
    const unsigned short* __restrict__ emb_bf,
    const float* __restrict__ b_in, const float* __restrict__ b_out,
    const unsigned short* __restrict__ w_sw,
    unsigned short* __restrict__ cs, float* __restrict__ out,
    int e, int row0, unsigned short (*Abuf)[136], int tid) {
  const int lane = tid & 63;
  const int wave = tid >> 6;
  const int coll = lane & 15;
  const int quad = lane >> 4;

  // per-lane A-row (row = coll of this wave's 16-row tile)
  const int garow = row0 + wave * 16 + coll;
  const int valid = garow < e;
  const int m = valid ? mask[garow] : 0;
  const int idx = valid ? x[garow] * m : 0;

  // ---- issue all A-fragment loads up front (hide gather latency) ----
  const unsigned short* arow = emb_bf + (size_t)idx * 128 + quad * 8;
  bf16x8 ea0 = ldz(arow, m);
  bf16x8 ea1 = ldz(arow + 32, m);
  bf16x8 ea2 = ldz(arow + 64, m);
  bf16x8 ea3 = ldz(arow + 96, m);
  bf16x8 ca0, ca1, ca2, ca3;
  if (!LEAF) {
    // childsum row of THIS node, produced by the child-level kernel.
    // garow may exceed e for partial tiles but stays < NPAR (see tail notes);
    // ldz zeroes those lanes.
    const unsigned short* crow = cs + (size_t)garow * 128 + quad * 8;
    ca0 = ldz(crow, valid);
    ca1 = ldz(crow + 32, valid);
    ca2 = ldz(crow + 64, valid);
    ca3 = ldz(crow + 96, valid);
  }

  f32x4 acc[8];
#pragma unroll
  for (int nt = 0; nt < 8; ++nt) acc[nt] = (f32x4){0.f, 0.f, 0.f, 0.f};

  // ---- GEMM 1: emb @ W_in ----
  mfma_row8(acc, ea0, w_sw, lane);
  mfma_row8(acc, ea1, w_sw + 4096, lane);
  mfma_row8(acc, ea2, w_sw + 8192, lane);
  mfma_row8(acc, ea3, w_sw + 12288, lane);

  // ---- GEMM 2: childsum @ U (accumulates into same acc) ----
  if (!LEAF) {
    mfma_row8(acc, ca0, w_sw + 16384, lane);
    mfma_row8(acc, ca1, w_sw + 20480, lane);
    mfma_row8(acc, ca2, w_sw + 24576, lane);
    mfma_row8(acc, ca3, w_sw + 28672, lane);
  }

  // ---- epilogue 1: + m*b_in, fast tanh; h -> LDS (wave-private) ----
  float binv[8];
#pragma unroll
  for (int nt = 0; nt < 8; ++nt) binv[nt] = b_in[nt * 16 + coll];
#pragma unroll
  for (int r2 = 0; r2 < 4; ++r2) {
    const int rowl = wave * 16 + quad * 4 + r2;  // C layout: row=quad*4+reg
    const int grow = row0 + rowl;
    const float mval = (grow < e) ? (float)mask[grow] : 0.f;
#pragma unroll
    for (int nt = 0; nt < 8; ++nt) {
      float t = acc[nt][r2] + mval * binv[nt];
      Abuf[rowl][nt * 16 + coll] = f2bf(fast_tanh(t));
    }
  }
  __builtin_amdgcn_wave_barrier();

  // ---- childsum production: wave's 16 rows = 2 complete parents ----
  // (row0-1 is divisible by 8 for every level; root tile row0==0 skips)
  if (row0 > 0) {
    const int j = lane >> 5;              // parent 0/1 within wave
    const int c4 = (lane & 31) * 4;       // ushort col 0,4,...,124
    const int childrow0 = row0 + (wave * 2 + j) * 8;
    if (childrow0 < e) {
      const int lr0 = wave * 16 + j * 8;
      f32x2 sA = {0.f, 0.f}, sB = {0.f, 0.f};
#pragma unroll
      for (int r = 0; r < 8; ++r) {       // children ascending: same fp32
        const unsigned int* pr =          // summation order as before
            (const unsigned int*)&Abuf[lr0 + r][c4];
        unsigned int u0 = pr[0], u1 = pr[1];
        union { unsigned int u; float f; } l0, h0, l1, h1;
        l0.u = u0 << 16; h0.u = u0 & 0xffff0000u;
        l1.u = u1 << 16; h1.u = u1 & 0xffff0000u;
        sA += (f32x2){l0.f, h0.f};
        sB += (f32x2){l1.f, h1.f};
      }
      uint2v w;
      w.x = pk2bf(sA[0], sA[1]);
      w.y = pk2bf(sB[0], sB[1]);
      const int p = ((row0 - 1) >> 3) + wave * 2 + j;
      *(uint2v*)(cs + (size_t)p * 128 + c4) = w;
    }
  }

  // ---- GEMM 3: out = h @ W_out + b_out (A frags transposed via LDS) ----
  f32x4 oacc[8];
#pragma unroll
  for (int nt = 0; nt < 8; ++nt) oacc[nt] = (f32x4){0.f, 0.f, 0.f, 0.f};
  const unsigned short* ab = &Abuf[wave * 16][0] + coll * 136 + quad * 8;
#pragma unroll
  for (int kt = 0; kt < 4; ++kt) {
    bf16x8 a = *(const bf16x8*)(ab + kt * 32);
    mfma_row8(oacc, a, w_sw + 32768 + kt * 4096, lane);
  }

  float boutv[8];
#pragma unroll
  for (int nt = 0; nt < 8; ++nt) boutv[nt] = b_out[nt * 16 + coll];
#pragma unroll
  for (int r2 = 0; r2 < 4; ++r2) {
    const int rowl = wave * 16 + quad * 4 + r2;
    const int grow = row0 + rowl;
    if (grow < e) {
#pragma unroll
      for (int nt = 0; nt < 8; ++nt)
        out[(size_t)grow * 128 + nt * 16 + coll] = oacc[nt][r2] + boutv[nt];
    }
  }
}

template <bool LEAF>
__global__ __launch_bounds__(256) void level_kernel(
    const int* __restrict__ x, const int* __restrict__ mask,
    const unsigned short* __restrict__ emb_bf, const float* __restrict__ b_in,
    const float* __restrict__ b_out, const unsigned short* __restrict__ w_sw,
    unsigned short* __restrict__ cs, float* __restrict__ out, int s, int e) {
  __shared__ __align__(16) unsigned short Abuf[64][136];
  tile_body<LEAF>(x, mask, emb_bf, b_in, b_out, w_sw, cs, out, e,
                  s + blockIdx.x * 64, Abuf, threadIdx.x);
}

// Levels 2 (rows 9..72), 1 (rows 1..8), 0 (row 0) in one block.
// __syncthreads between tiles: barrier's vmcnt(0) drain + L1 behavior
// (cs lines written here were never previously read this dispatch) makes
// the same-block global childsum RAW safe — same argument as the h-array
// RAW in the previous (passing) version.
__global__ __launch_bounds__(256) void tail_kernel(
    const int* __restrict__ x, const int* __restrict__ mask,
    const unsigned short* __restrict__ emb_bf, const float* __restrict__ b_in,
    const float* __restrict__ b_out, const unsigned short* __restrict__ w_sw,
    unsigned short* __restrict__ cs, float* __restrict__ out) {
  __shared__ __align__(16) unsigned short Abuf[64][136];
  tile_body<false>(x, mask, emb_bf, b_in, b_out, w_sw, cs, out, 73, 9, Abuf,
                   threadIdx.x);
  __syncthreads();
  tile_body<false>(x, mask, emb_bf, b_in, b_out, w_sw, cs, out, 9, 1, Abuf,
                   threadIdx.x);
  __syncthreads();
  tile_body<false>(x, mask, emb_bf, b_in, b_out, w_sw, cs, out, 1, 0, Abuf,
                   threadIdx.x);
}

extern "C" void kernel_launch(void* const* d_in, const int* in_sizes, int n_in,
                              void* d_out, int out_size, void* d_ws,
                              size_t ws_size, hipStream_t stream) {
  const int* x = (const int*)d_in[0];
  const int* mask = (const int*)d_in[1];
  // d_in[2] = children: implied (child rows of i are i*8+1..i*8+8)
  const float* emb = (const float*)d_in[3];
  const float* W_in = (const float*)d_in[4];
  const float* b_in = (const float*)d_in[5];
  const float* U = (const float*)d_in[6];
  const float* W_out = (const float*)d_in[7];
  const float* b_out = (const float*)d_in[8];
  float* out = (float*)d_out;

  // ws layout: emb bf16 [32000*128] | childsum bf16 [NPAR*128] | w_sw [3*16384]
  unsigned short* emb_bf = (unsigned short*)d_ws;
  unsigned short* cs = emb_bf + (size_t)32000 * 128;
  unsigned short* w_sw = cs + (size_t)NPAR * 128;

  prep_kernel<<<2192, 256, 0, stream>>>(W_in, U, W_out, emb, w_sw, emb_bf);

  // leaf level l=6: rows 37449..299592 -> childsum for parents 4681..37448
  level_kernel<true><<<4096, 256, 0, stream>>>(x, mask, emb_bf, b_in, b_out,
                                               w_sw, cs, out, 37449, 299593);
  // l=5
  level_kernel<false><<<512, 256, 0, stream>>>(x, mask, emb_bf, b_in, b_out,
                                               w_sw, cs, out, 4681, 37449);
  // l=4
  level_kernel<false><<<64, 256, 0, stream>>>(x, mask, emb_bf, b_in, b_out,
                                              w_sw, cs, out, 585, 4681);
  // l=3
  level_kernel<false><<<8, 256, 0, stream>>>(x, mask, emb_bf, b_in, b_out,
                                             w_sw, cs, out, 73, 585);
  // l=2,1,0 merged
  tail_kernel<<<1, 256, 0, stream>>>(x, mask, emb_bf, b_in, b_out, w_sw, cs,
                                     out);
}